// Round 8
// baseline (201.668 us; speedup 1.0000x reference)
//
#include <hip/hip_runtime.h>

// CTC forward loss, MI355X. R8: producer/consumer wave split.
// Block = 256 threads, one block per example.
//   Waves 1-3 (builders): per 64-row chunk, gather pred[t, col_j], scale by
//     log2(e), exp2, write LDS tables tb13[buf][row][j]=(e1,e3) (b64) and
//     tbB[buf][row] (blank). Double-buffered; one __syncthreads per chunk.
//   Wave 0 (chain): linear-domain alpha recurrence with per-lane pow2 renorm
//     every 8 steps (R7 math, bit-identical). Per step: 1 ds_read_b64 +
//     1 broadcast ds_read_b32 (prefetched 2 rows ahead) + ~26 VALU.
//     NO transcendentals, NO global loads, NO vmcnt on the chain.
// Chain lane l owns states 4l+1..4l+4; state 0 = a0 (uniform). Cross-lane
// via DPP wave_shr:1. Reduce folded in via atomicAdd (memsetAsync'd out).

static constexpr float LOG2E_F = 1.4426950408889634f;
static constexpr float LN2_F   = 0.6931471805599453f;

#if __has_builtin(__builtin_amdgcn_exp2f)
#define FEXP2(x) __builtin_amdgcn_exp2f(x)
#else
#define FEXP2(x) exp2f(x)
#endif
#if __has_builtin(__builtin_amdgcn_logf)
#define FLOG2(x) __builtin_amdgcn_logf(x)
#else
#define FLOG2(x) log2f(x)
#endif

__device__ __forceinline__ float dpp_shr1(float src, float fill) {
  return __int_as_float(__builtin_amdgcn_update_dpp(
      __float_as_int(fill), __float_as_int(src), 0x138, 0xF, 0xF, false));
}
__device__ __forceinline__ int dpp_shr1_i(int src, int fill) {
  return __builtin_amdgcn_update_dpp(fill, src, 0x138, 0xF, 0xF, false);
}

template <int T, int C, int L>
__global__ __launch_bounds__(256) void ctc_alpha_tab(
    const float* __restrict__ pred,      // (B,T,C) log-probs
    const int*   __restrict__ targets,   // (B,L)
    const int*   __restrict__ pred_len,  // (B)
    const int*   __restrict__ tgt_len,   // (B)
    float*       __restrict__ out,       // scalar accumulator (pre-zeroed)
    float inv_B)
{
  constexpr int S   = 2 * L + 1;         // 257
  constexpr int NCH = T / 64;            // 16 chunks of 64 rows

  __shared__ float2 tb13[2][64][64];     // [buf][row][j] = (e1, e3)  64 KiB
  __shared__ float  tbB [2][64];         // blank emission per row
  __shared__ float  afin[S];

  const int b   = blockIdx.x;
  const int tid = threadIdx.x;
  const int wid = tid >> 6;
  const int l   = tid & 63;

  const float* __restrict__ prow = pred + (size_t)b * T * C;
  const int plen = pred_len[b];
  int tl = tgt_len[b]; if (tl < 1) tl = 1; if (tl > L) tl = L;
  const int tmax = plen < T ? plen : T;

  // ---- builder setup (waves 1-3): fixed column j, rows t = btr + 3i ----
  int bj = 0, btr = 0, bc1 = 0, bc3 = 0;
  if (wid) {
    const int gl = (wid - 1) * 64 + l;   // 0..191
    bj  = gl & 63;
    btr = gl >> 6;                       // 0,1,2 (whole-wave uniform)
    bc1 = targets[b * L + 2 * bj];
    bc3 = targets[b * L + 2 * bj + 1];
  }

  auto build = [&](int c) {
    const int buf = c & 1;
    const float* base = prow + (size_t)c * 64 * C;
#pragma unroll
    for (int i = 0; i < 22; ++i) {
      const int t = btr + 3 * i;
      if (t < 64) {
        const float v1 = base[t * C + bc1];
        const float v3 = base[t * C + bc3];
        tb13[buf][t][bj] = make_float2(FEXP2(v1 * LOG2E_F),
                                       FEXP2(v3 * LOG2E_F));
      }
    }
    if (wid == 1) tbB[buf][l] = FEXP2(base[l * C] * LOG2E_F);
  };

  // ---- chain setup (wave 0): skip coefficients only ----
  float k1 = 0.0f, k3 = 0.0f;
  if (!wid) {
    const int c1 = targets[b * L + 2 * l];
    const int c3 = targets[b * L + 2 * l + 1];
    k1 = (l == 0) ? 0.0f : ((c1 != targets[b * L + 2 * l - 1]) ? 1.0f : 0.0f);
    k3 = (c3 != c1) ? 1.0f : 0.0f;
  }

  float a0 = 0.0f, x1 = 0.0f, x2 = 0.0f, x3 = 0.0f, x4 = 0.0f;
  int   E  = 0;

  auto step = [&](float Eb, float E1, float E3) {    // linear emission factors
    const int Eprev = dpp_shr1_i(E, E);              // lane0: own E -> dE=0
    const uint32_t orx = __float_as_uint(x1) | __float_as_uint(x2) |
                         __float_as_uint(x3) | __float_as_uint(x4);
    if (orx == 0u) E = Eprev;                        // dead lane adopts E
    int dE = Eprev - E;
    dE = dE < -126 ? -126 : (dE > 126 ? 126 : dE);
    const float sc = __int_as_float((dE + 127) << 23);   // exact 2^dE
    const float P4 = dpp_shr1(x4, a0) * sc;          // prev-lane state 4l
    const float P3 = dpp_shr1(x3, x3) * sc;          // prev-lane state 4l-1
    const float t1 = fmaf(k1, P3, x1 + P4);
    const float t2 = x2 + x1;
    const float t3 = fmaf(k3, x1, x3 + x2);
    const float t4 = x4 + x3;
    x1 = t1 * E1; x2 = t2 * Eb; x3 = t3 * E3; x4 = t4 * Eb;
    a0 *= Eb;
  };

  auto renorm = [&]() {                              // exact pow2 rescale
    const float m = fmaxf(fmaxf(fmaxf(x1, x2), fmaxf(x3, x4)), a0);
    int ebi = (int)((__float_as_uint(m) >> 23) & 0xffu);
    if (ebi == 0) ebi = 126;                         // dead/denorm: no-op
    const float sc = __uint_as_float((uint32_t)(253 - ebi) << 23);
    x1 *= sc; x2 *= sc; x3 *= sc; x4 *= sc; a0 *= sc;
    E += ebi - 126;
  };

  if (wid) build(0);
  __syncthreads();

  for (int c = 0; c < NCH; ++c) {
    if (wid) {
      if (c + 1 < NCH) build(c + 1);
    } else {
      const int buf = c & 1;
      int r = c * 64;                                // global row of slot A
      float2 fA = tb13[buf][0][l];  float bA = tbB[buf][0];
      float2 fB = tb13[buf][1][l];  float bB = tbB[buf][1];
      for (int p = 0; p < 32; ++p, r += 2) {
        if (r && !(r & 7)) renorm();
        if (r == 0) {                                // t=0 init from table
          a0 = bA; x1 = (l == 0) ? fA.x : 0.0f;
          x2 = x3 = x4 = 0.0f; E = 0;
        } else if (r < tmax) {
          step(bA, fA.x, fA.y);
        }
        if (p < 31) { const int lr = (r + 2) & 63;
                      fA = tb13[buf][lr][l]; bA = tbB[buf][lr]; }
        if (r + 1 < tmax) step(bB, fB.x, fB.y);
        if (p < 31) { const int lr = (r + 3) & 63;
                      fB = tb13[buf][lr][l]; bB = tbB[buf][lr]; }
      }
    }
    __syncthreads();
  }

  // readout: log2(alpha) = log2(x) + E; lse2 of states 2tl-1, 2tl
  if (!wid) {
    const float fE = (float)E;
    afin[4 * l + 1] = FLOG2(x1) + fE;
    afin[4 * l + 2] = FLOG2(x2) + fE;
    afin[4 * l + 3] = FLOG2(x3) + fE;
    afin[4 * l + 4] = FLOG2(x4) + fE;
    if (l == 0) afin[0] = FLOG2(a0) + fE;
  }
  __syncthreads();
  if (tid == 0) {
    const float l1 = afin[2 * tl - 1];
    const float l2 = afin[2 * tl];
    const float mm = fmaxf(l1, l2);
    const float ls = mm + FLOG2(FEXP2(l1 - mm) + FEXP2(l2 - mm));
    float per = -(ls * LN2_F);
    if (!(per < 1e29f)) per = 0.0f;                  // zero_infinity (inf/NaN)
    atomicAdd(out, (per / (float)tl) * inv_B);
  }
}

extern "C" void kernel_launch(void* const* d_in, const int* in_sizes, int n_in,
                              void* d_out, int out_size, void* d_ws, size_t ws_size,
                              hipStream_t stream)
{
  const float* pred    = (const float*)d_in[0];
  const int*   targets = (const int*)d_in[1];
  const int*   plen    = (const int*)d_in[2];
  const int*   tlen    = (const int*)d_in[3];
  float*       out     = (float*)d_out;

  constexpr int B = 128, T = 1024, C = 128, L = 128;

  hipMemsetAsync(out, 0, sizeof(float), stream);
  hipLaunchKernelGGL((ctc_alpha_tab<T, C, L>), dim3(B), dim3(256), 0, stream,
                     pred, targets, plen, tlen, out, 1.0f / (float)B);
}